// Round 1
// baseline (146.083 us; speedup 1.0000x reference)
//
#include <hip/hip_runtime.h>

#define WIN    7
#define NPW    49
#define Hc     512
#define Wc     512
#define OH     506
#define OW     506
#define NPIX   (Hc * Wc)
#define BATCH  64

#define CHUNKS   16            // min/max chunks per sample
#define TILE_OH  16
#define TILE_OW  64
#define IN_H     (TILE_OH + WIN - 1)   // 22
#define IN_W     (TILE_OW + WIN - 1)   // 70
#define GX       8                     // ceil(506/64)
#define GY       32                    // ceil(506/16)
#define NPART    (BATCH * GX * GY)     // 16384

// ---------------- Kernel 1: per-(sample,chunk) min/max partials -------------
__global__ __launch_bounds__(256) void mm_part_kernel(
    const float* __restrict__ X, const float* __restrict__ Y,
    float* __restrict__ part)
{
    int blk = blockIdx.x;            // 0 .. BATCH*CHUNKS-1
    int b   = blk >> 4;              // sample
    int ch  = blk & 15;              // chunk
    size_t base = (size_t)b * NPIX + (size_t)ch * (NPIX / CHUNKS);
    const float4* x4 = (const float4*)(X + base);
    const float4* y4 = (const float4*)(Y + base);
    const int n4 = (NPIX / CHUNKS) / 4;   // 4096

    float mn = 1e38f, mx = -1e38f;
    for (int i = threadIdx.x; i < n4; i += 256) {
        float4 a = x4[i];
        float4 c = y4[i];
        mn = fminf(mn, fminf(fminf(a.x, a.y), fminf(a.z, a.w)));
        mx = fmaxf(mx, fmaxf(fmaxf(a.x, a.y), fmaxf(a.z, a.w)));
        mn = fminf(mn, fminf(fminf(c.x, c.y), fminf(c.z, c.w)));
        mx = fmaxf(mx, fmaxf(fmaxf(c.x, c.y), fmaxf(c.z, c.w)));
    }
    #pragma unroll
    for (int off = 1; off < 64; off <<= 1) {
        mn = fminf(mn, __shfl_xor(mn, off, 64));
        mx = fmaxf(mx, __shfl_xor(mx, off, 64));
    }
    __shared__ float smn[4], smx[4];
    int lane = threadIdx.x & 63, wid = threadIdx.x >> 6;
    if (lane == 0) { smn[wid] = mn; smx[wid] = mx; }
    __syncthreads();
    if (threadIdx.x == 0) {
        mn = fminf(fminf(smn[0], smn[1]), fminf(smn[2], smn[3]));
        mx = fmaxf(fmaxf(smx[0], smx[1]), fmaxf(smx[2], smx[3]));
        part[2 * blk]     = mn;
        part[2 * blk + 1] = mx;
    }
}

// ---------------- Kernel 2: fold chunk partials -> C1, C2 per sample --------
__global__ void mm_final_kernel(const float* __restrict__ part,
                                float* __restrict__ c12)
{
    int b = threadIdx.x;
    if (b < BATCH) {
        float mn = 1e38f, mx = -1e38f;
        for (int ch = 0; ch < CHUNKS; ++ch) {
            mn = fminf(mn, part[2 * (b * CHUNKS + ch)]);
            mx = fmaxf(mx, part[2 * (b * CHUNKS + ch) + 1]);
        }
        float dr = mx - mn;
        float c1 = 0.01f * dr;
        float c2 = 0.03f * dr;
        c12[2 * b]     = c1 * c1;
        c12[2 * b + 1] = c2 * c2;
    }
}

// ---------------- Kernel 3: tiled separable SSIM ----------------------------
__global__ __launch_bounds__(256) void ssim_tile_kernel(
    const float* __restrict__ X, const float* __restrict__ Y,
    const float* __restrict__ c12, float* __restrict__ part)
{
    __shared__ float sx[IN_H][IN_W + 2];       // 22 x 72 (pad)
    __shared__ float sy[IN_H][IN_W + 2];
    __shared__ float hs[5][IN_H][TILE_OW];     // horizontal 7-sums, 5 stats

    const int b   = blockIdx.z;
    const int oy0 = blockIdx.y * TILE_OH;
    const int ox0 = blockIdx.x * TILE_OW;
    const float* xb = X + (size_t)b * NPIX;
    const float* yb = Y + (size_t)b * NPIX;
    const int tid = threadIdx.x;

    // stage input tile (+halo) into LDS, zero-fill out of range
    for (int idx = tid; idx < IN_H * IN_W; idx += 256) {
        int r = idx / IN_W;
        int c = idx - r * IN_W;
        int iy = oy0 + r, ix = ox0 + c;
        float xv = 0.f, yv = 0.f;
        if (iy < Hc && ix < Wc) {
            xv = xb[iy * Wc + ix];
            yv = yb[iy * Wc + ix];
        }
        sx[r][c] = xv;
        sy[r][c] = yv;
    }
    __syncthreads();

    // horizontal 7-window sums of x, y, xx, yy, xy
    for (int idx = tid; idx < IN_H * TILE_OW; idx += 256) {
        int r = idx >> 6, c = idx & 63;
        float a = 0.f, s = 0.f, axx = 0.f, ayy = 0.f, axy = 0.f;
        #pragma unroll
        for (int k = 0; k < WIN; ++k) {
            float xv = sx[r][c + k];
            float yv = sy[r][c + k];
            a   += xv;      s   += yv;
            axx += xv * xv; ayy += yv * yv; axy += xv * yv;
        }
        hs[0][r][c] = a;   hs[1][r][c] = s;
        hs[2][r][c] = axx; hs[3][r][c] = ayy; hs[4][r][c] = axy;
    }
    __syncthreads();

    const float C1 = c12[2 * b];
    const float C2 = c12[2 * b + 1];
    float acc = 0.f;

    // vertical 7-window sums + SSIM
    for (int idx = tid; idx < TILE_OH * TILE_OW; idx += 256) {
        int r = idx >> 6, c = idx & 63;
        int oy = oy0 + r, ox = ox0 + c;
        if (oy < OH && ox < OW) {
            float Sx = 0.f, Sy = 0.f, Sxx = 0.f, Syy = 0.f, Sxy = 0.f;
            #pragma unroll
            for (int k = 0; k < WIN; ++k) {
                Sx  += hs[0][r + k][c];
                Sy  += hs[1][r + k][c];
                Sxx += hs[2][r + k][c];
                Syy += hs[3][r + k][c];
                Sxy += hs[4][r + k][c];
            }
            const float inv  = 1.0f / 49.0f;
            const float covn = 49.0f / 48.0f;
            float ux  = Sx * inv, uy = Sy * inv;
            float vx  = covn * (Sxx * inv - ux * ux);
            float vy  = covn * (Syy * inv - uy * uy);
            float vxy = covn * (Sxy * inv - ux * uy);
            float A1v = 2.f * ux * uy + C1;
            float A2v = 2.f * vxy + C2;
            float B1v = ux * ux + uy * uy + C1;
            float B2v = vx + vy + C2;
            acc += (A1v * A2v) / (B1v * B2v);
        }
    }

    // block reduce (deterministic butterfly + LDS)
    #pragma unroll
    for (int off = 1; off < 64; off <<= 1)
        acc += __shfl_xor(acc, off, 64);
    __shared__ float sacc[4];
    int lane = tid & 63, wid = tid >> 6;
    if (lane == 0) sacc[wid] = acc;
    __syncthreads();
    if (tid == 0) {
        float s = sacc[0] + sacc[1] + sacc[2] + sacc[3];
        part[(blockIdx.z * GY + blockIdx.y) * GX + blockIdx.x] = s;
    }
}

// ---------------- Kernel 4: final deterministic f64 reduction ---------------
__global__ __launch_bounds__(256) void final_reduce_kernel(
    const float* __restrict__ part, float* __restrict__ out)
{
    __shared__ double sd[256];
    double s = 0.0;
    for (int i = threadIdx.x; i < NPART; i += 256)
        s += (double)part[i];
    sd[threadIdx.x] = s;
    __syncthreads();
    for (int off = 128; off > 0; off >>= 1) {
        if (threadIdx.x < off) sd[threadIdx.x] += sd[threadIdx.x + off];
        __syncthreads();
    }
    if (threadIdx.x == 0)
        out[0] = (float)(sd[0] / ((double)BATCH * OH * OW));
}

extern "C" void kernel_launch(void* const* d_in, const int* in_sizes, int n_in,
                              void* d_out, int out_size, void* d_ws, size_t ws_size,
                              hipStream_t stream) {
    const float* X = (const float*)d_in[0];
    const float* Y = (const float*)d_in[1];
    float* out = (float*)d_out;
    float* ws  = (float*)d_ws;

    float* mmpart = ws;                  // 2 * BATCH * CHUNKS = 2048 floats
    float* c12    = ws + 2048;           // 2 * BATCH = 128 floats
    float* part   = ws + 2048 + 128;     // NPART = 16384 floats

    mm_part_kernel<<<BATCH * CHUNKS, 256, 0, stream>>>(X, Y, mmpart);
    mm_final_kernel<<<1, 64, 0, stream>>>(mmpart, c12);
    dim3 grid(GX, GY, BATCH);
    ssim_tile_kernel<<<grid, 256, 0, stream>>>(X, Y, c12, part);
    final_reduce_kernel<<<1, 256, 0, stream>>>(part, out);
}

// Round 2
// 120.844 us; speedup vs baseline: 1.2089x; 1.2089x over previous
//
#include <hip/hip_runtime.h>

#define Hc     512
#define Wc     512
#define OH     506
#define OW     506
#define NPIX   (Hc * Wc)
#define BATCH  64
#define CHUNKS 16

#define T_OW   64
#define T_OH   32
#define IN_H   (T_OH + 6)          // 38
#define GX     8                   // ceil(506/64)
#define GY     16                  // ceil(506/32)
#define NPART  (BATCH * GX * GY)   // 8192
#define NRUNS  (IN_H * 16)         // 608 column-runs of 4 per tile

// ---------------- Kernel 1: per-(sample,chunk) min/max partials -------------
__global__ __launch_bounds__(256) void mm_part_kernel(
    const float* __restrict__ X, const float* __restrict__ Y,
    float* __restrict__ part)
{
    int blk = blockIdx.x;            // 0 .. BATCH*CHUNKS-1
    int b   = blk >> 4;
    int ch  = blk & 15;
    size_t base = (size_t)b * NPIX + (size_t)ch * (NPIX / CHUNKS);
    const float4* x4 = (const float4*)(X + base);
    const float4* y4 = (const float4*)(Y + base);
    const int n4 = (NPIX / CHUNKS) / 4;   // 4096

    float mn = 1e38f, mx = -1e38f;
    for (int i = threadIdx.x; i < n4; i += 256) {
        float4 a = x4[i];
        float4 c = y4[i];
        mn = fminf(mn, fminf(fminf(a.x, a.y), fminf(a.z, a.w)));
        mx = fmaxf(mx, fmaxf(fmaxf(a.x, a.y), fmaxf(a.z, a.w)));
        mn = fminf(mn, fminf(fminf(c.x, c.y), fminf(c.z, c.w)));
        mx = fmaxf(mx, fmaxf(fmaxf(c.x, c.y), fmaxf(c.z, c.w)));
    }
    #pragma unroll
    for (int off = 1; off < 64; off <<= 1) {
        mn = fminf(mn, __shfl_xor(mn, off, 64));
        mx = fmaxf(mx, __shfl_xor(mx, off, 64));
    }
    __shared__ float smn[4], smx[4];
    int lane = threadIdx.x & 63, wid = threadIdx.x >> 6;
    if (lane == 0) { smn[wid] = mn; smx[wid] = mx; }
    __syncthreads();
    if (threadIdx.x == 0) {
        mn = fminf(fminf(smn[0], smn[1]), fminf(smn[2], smn[3]));
        mx = fmaxf(fmaxf(smx[0], smx[1]), fmaxf(smx[2], smx[3]));
        part[2 * blk]     = mn;
        part[2 * blk + 1] = mx;
    }
}

// ---------------- Kernel 3: load-fused horizontal + sliding vertical SSIM ---
__global__ __launch_bounds__(256) void ssim_kernel(
    const float* __restrict__ X, const float* __restrict__ Y,
    const float* __restrict__ mmpart, float* __restrict__ part)
{
    __shared__ float hs[4][IN_H][T_OW];   // 38912 B

    const int b   = blockIdx.z;
    const int oy0 = blockIdx.y * T_OH;
    const int ox0 = blockIdx.x * T_OW;
    const float* xb = X + (size_t)b * NPIX;
    const float* yb = Y + (size_t)b * NPIX;
    const int tid = threadIdx.x;

    // fold chunk min/max -> C1, C2 (uniform across block; SALU-friendly)
    float mn = 1e38f, mx = -1e38f;
    #pragma unroll
    for (int ch = 0; ch < CHUNKS; ++ch) {
        mn = fminf(mn, mmpart[2 * (b * CHUNKS + ch)]);
        mx = fmaxf(mx, mmpart[2 * (b * CHUNKS + ch) + 1]);
    }
    const float dr = mx - mn;
    const float C1 = (0.01f * dr) * (0.01f * dr);
    const float C2 = (0.03f * dr) * (0.03f * dr);

    const bool edge = (ox0 + T_OW + 6 > Wc);   // only last column-tile

    // ---- phase 1: global -> registers -> horizontal 7-sums (sliding) ------
    for (int q = tid; q < NRUNS; q += 256) {
        int r  = q >> 4;
        int cg = q & 15;
        int c0 = cg * 4;
        int iy = oy0 + r; if (iy > Hc - 1) iy = Hc - 1;
        const float* xr = xb + (size_t)iy * Wc;
        const float* yr = yb + (size_t)iy * Wc;
        float xv[10], yv[10];
        if (!edge) {
            float4 a0 = *(const float4*)(xr + ox0 + c0);
            float4 a1 = *(const float4*)(xr + ox0 + c0 + 4);
            float2 a2 = *(const float2*)(xr + ox0 + c0 + 8);
            xv[0]=a0.x; xv[1]=a0.y; xv[2]=a0.z; xv[3]=a0.w;
            xv[4]=a1.x; xv[5]=a1.y; xv[6]=a1.z; xv[7]=a1.w;
            xv[8]=a2.x; xv[9]=a2.y;
            float4 b0 = *(const float4*)(yr + ox0 + c0);
            float4 b1 = *(const float4*)(yr + ox0 + c0 + 4);
            float2 b2 = *(const float2*)(yr + ox0 + c0 + 8);
            yv[0]=b0.x; yv[1]=b0.y; yv[2]=b0.z; yv[3]=b0.w;
            yv[4]=b1.x; yv[5]=b1.y; yv[6]=b1.z; yv[7]=b1.w;
            yv[8]=b2.x; yv[9]=b2.y;
        } else {
            #pragma unroll
            for (int j = 0; j < 10; ++j) {
                int ix = ox0 + c0 + j; if (ix > Wc - 1) ix = Wc - 1;
                xv[j] = xr[ix]; yv[j] = yr[ix];
            }
        }
        float pxy[10], pss[10];
        #pragma unroll
        for (int j = 0; j < 10; ++j) {
            pxy[j] = xv[j] * yv[j];
            pss[j] = xv[j] * xv[j] + yv[j] * yv[j];
        }
        float Sx = 0.f, Sy = 0.f, Sxy = 0.f, Sss = 0.f;
        #pragma unroll
        for (int j = 0; j < 7; ++j) {
            Sx += xv[j]; Sy += yv[j]; Sxy += pxy[j]; Sss += pss[j];
        }
        hs[0][r][c0] = Sx; hs[1][r][c0] = Sy;
        hs[2][r][c0] = Sxy; hs[3][r][c0] = Sss;
        #pragma unroll
        for (int s = 0; s < 3; ++s) {
            Sx  += xv[7 + s]  - xv[s];
            Sy  += yv[7 + s]  - yv[s];
            Sxy += pxy[7 + s] - pxy[s];
            Sss += pss[7 + s] - pss[s];
            hs[0][r][c0 + 1 + s] = Sx;  hs[1][r][c0 + 1 + s] = Sy;
            hs[2][r][c0 + 1 + s] = Sxy; hs[3][r][c0 + 1 + s] = Sss;
        }
    }
    __syncthreads();

    // ---- phase 2: vertical sliding 7-sums + SSIM ---------------------------
    const int c  = tid & 63;
    const int rg = tid >> 6;
    const int r0 = rg * 8;
    float Sx = 0.f, Sy = 0.f, Sxy = 0.f, Sss = 0.f;
    #pragma unroll
    for (int k = 0; k < 7; ++k) {
        Sx  += hs[0][r0 + k][c];
        Sy  += hs[1][r0 + k][c];
        Sxy += hs[2][r0 + k][c];
        Sss += hs[3][r0 + k][c];
    }
    const float inv  = 1.0f / 49.0f;
    const float covn = 49.0f / 48.0f;
    const int ox = ox0 + c;
    float acc = 0.f;
    #pragma unroll
    for (int j = 0; j < 8; ++j) {
        int oy = oy0 + r0 + j;
        if (oy < OH && ox < OW) {
            float ux   = Sx * inv, uy = Sy * inv;
            float uxuy = ux * uy;
            float u2   = ux * ux + uy * uy;
            float vxy  = covn * (Sxy * inv - uxuy);
            float vsum = covn * (Sss * inv - u2);
            float A1v  = 2.f * uxuy + C1;
            float A2v  = 2.f * vxy + C2;
            float B1v  = u2 + C1;
            float B2v  = vsum + C2;
            acc += (A1v * A2v) * __builtin_amdgcn_rcpf(B1v * B2v);
        }
        if (j < 7) {
            Sx  += hs[0][r0 + j + 7][c] - hs[0][r0 + j][c];
            Sy  += hs[1][r0 + j + 7][c] - hs[1][r0 + j][c];
            Sxy += hs[2][r0 + j + 7][c] - hs[2][r0 + j][c];
            Sss += hs[3][r0 + j + 7][c] - hs[3][r0 + j][c];
        }
    }

    // ---- deterministic block reduce ---------------------------------------
    #pragma unroll
    for (int off = 1; off < 64; off <<= 1)
        acc += __shfl_xor(acc, off, 64);
    __shared__ float sacc[4];
    int lane = tid & 63, wid = tid >> 6;
    if (lane == 0) sacc[wid] = acc;
    __syncthreads();
    if (tid == 0) {
        float s = sacc[0] + sacc[1] + sacc[2] + sacc[3];
        part[((size_t)b * GY + blockIdx.y) * GX + blockIdx.x] = s;
    }
}

// ---------------- Kernel 4: final deterministic f64 reduction ---------------
__global__ __launch_bounds__(256) void final_reduce_kernel(
    const float* __restrict__ part, float* __restrict__ out)
{
    __shared__ double sd[256];
    double s = 0.0;
    for (int i = threadIdx.x; i < NPART; i += 256)
        s += (double)part[i];
    sd[threadIdx.x] = s;
    __syncthreads();
    for (int off = 128; off > 0; off >>= 1) {
        if (threadIdx.x < off) sd[threadIdx.x] += sd[threadIdx.x + off];
        __syncthreads();
    }
    if (threadIdx.x == 0)
        out[0] = (float)(sd[0] / ((double)BATCH * OH * OW));
}

extern "C" void kernel_launch(void* const* d_in, const int* in_sizes, int n_in,
                              void* d_out, int out_size, void* d_ws, size_t ws_size,
                              hipStream_t stream) {
    const float* X = (const float*)d_in[0];
    const float* Y = (const float*)d_in[1];
    float* out = (float*)d_out;
    float* ws  = (float*)d_ws;

    float* mmpart = ws;              // 2 * BATCH * CHUNKS = 2048 floats
    float* part   = ws + 2048;       // NPART = 8192 floats

    mm_part_kernel<<<BATCH * CHUNKS, 256, 0, stream>>>(X, Y, mmpart);
    dim3 grid(GX, GY, BATCH);
    ssim_kernel<<<grid, 256, 0, stream>>>(X, Y, mmpart, part);
    final_reduce_kernel<<<1, 256, 0, stream>>>(part, out);
}